// Round 17
// baseline (218.747 us; speedup 1.0000x reference)
//
#include <hip/hip_runtime.h>
#include <hip/hip_bf16.h>

#define N_NODES 65536
#define N_EDGES 524288

typedef __attribute__((ext_vector_type(8))) short bf16x8;
typedef __attribute__((ext_vector_type(4))) float f32x4;

__device__ __forceinline__ float bf2f(unsigned short u) {
    union { unsigned int i; float f; } v;
    v.i = ((unsigned int)u) << 16;
    return v.f;
}
__device__ __forceinline__ unsigned short f2bf(float f) {
    union { float f; unsigned int i; } v;
    v.f = f;
    unsigned int r = v.i + 0x7fff + ((v.i >> 16) & 1);  // round-to-nearest-even
    return (unsigned short)(r >> 16);
}

// ---------------- init: cnt=0, logits=0 ---------------------------------------
__global__ void init_k(int* __restrict__ cnt, float* __restrict__ logits) {
    int i = blockIdx.x * 256 + threadIdx.x;
    cnt[i] = 0;
    if (i < 512) logits[i] = 0.0f;
}

// ------- merged: in-degree count | f2b(wc1) | f2b(wc2) | wcomb PACKED ---------
// blocks [0,2048): cnt atomics ; [2048,3072): wc1 f2b ; [3072,3200): wc2 f2b ;
// [3200,3456): wcomb -> packed fragment order (nkt=4):
//   WTpk[((nb*4 + kt)*64 + l)*8 + ke] = WT[nb*16+(l&15)][kt*32+(l>>4)*8+ke]
__global__ void prep1_k(const int* __restrict__ dst, int* __restrict__ cnt,
                        const float* __restrict__ wc1, __hip_bfloat16* __restrict__ wc1bf,
                        const float* __restrict__ wc2, __hip_bfloat16* __restrict__ wc2bf,
                        const float* __restrict__ w1, const float* __restrict__ wg,
                        __hip_bfloat16* __restrict__ WTpk) {
    int bid = blockIdx.x;
    if (bid < 2048) {
        int e = bid * 256 + threadIdx.x;
        atomicAdd(&cnt[dst[e]], 1);
    } else if (bid < 3200) {
        const float* in;
        __hip_bfloat16* outp;
        int i;
        if (bid < 3072) { in = wc1; outp = wc1bf; i = (bid - 2048) * 1024 + threadIdx.x * 4; }
        else            { in = wc2; outp = wc2bf; i = (bid - 3072) * 1024 + threadIdx.x * 4; }
        float4 v = *(const float4*)(in + i);
        alignas(8) __hip_bfloat16 tmp[4] = {__float2bfloat16(v.x), __float2bfloat16(v.y),
                                            __float2bfloat16(v.z), __float2bfloat16(v.w)};
        *(ushort4*)((unsigned short*)outp + i) = *(const ushort4*)tmp;
    } else {
        int t = (bid - 3200) * 256 + threadIdx.x;  // 512*128
        int f = t >> 7, c = t & 127;
        float s = 0.f;
#pragma unroll 8
        for (int m = 0; m < 128; ++m) s += w1[c * 128 + m] * wg[m * 512 + f];
        int pk = ((((f >> 4) * 4 + (c >> 5)) * 64 + ((c >> 3) & 3) * 16 + (f & 15)) * 8) + (c & 7);
        WTpk[pk] = __float2bfloat16(s);
    }
}

// ------- hierarchical exclusive scan of cnt[65536] -> rp, cursor --------------
__global__ __launch_bounds__(256) void scan1_k(const int* __restrict__ cnt,
                                               int* __restrict__ rp,
                                               int* __restrict__ bsum) {
    __shared__ int s[256];
    int t = threadIdx.x, g = blockIdx.x * 256 + t;
    int v = cnt[g];
    s[t] = v;
    __syncthreads();
    for (int d = 1; d < 256; d <<= 1) {
        int u = (t >= d) ? s[t - d] : 0;
        __syncthreads();
        s[t] += u;
        __syncthreads();
    }
    rp[g] = s[t] - v;
    if (t == 255) bsum[blockIdx.x] = s[255];
}
__global__ __launch_bounds__(256) void scan2_k(int* __restrict__ bsum,
                                               int* __restrict__ rp) {
    __shared__ int s[256];
    int t = threadIdx.x;
    int v = bsum[t];
    s[t] = v;
    __syncthreads();
    for (int d = 1; d < 256; d <<= 1) {
        int u = (t >= d) ? s[t - d] : 0;
        __syncthreads();
        s[t] += u;
        __syncthreads();
    }
    bsum[t] = s[t] - v;
    if (t == 255) rp[65536] = s[255];
}
__global__ __launch_bounds__(256) void scan3_k(int* __restrict__ rp,
                                               const int* __restrict__ bsum,
                                               int* __restrict__ cursor) {
    int t = threadIdx.x, g = blockIdx.x * 256 + t;
    int r = rp[g] + bsum[blockIdx.x];
    rp[g] = r;
    cursor[g] = r;
}

// ------- scatter edges into dst-sorted CSR order, packed (src, w) -------------
__global__ void scatter_k(const int* __restrict__ src, const int* __restrict__ dst,
                          const float* __restrict__ w,
                          int* __restrict__ cursor, uint2* __restrict__ ep) {
    int e = blockIdx.x * 256 + threadIdx.x;
    int pos = atomicAdd(&cursor[dst[e]], 1);
    uint2 p;
    p.x = (unsigned int)src[e];
    p.y = __float_as_uint(w[e]);
    ep[pos] = p;
}

// ------- fused: degree row-sum (parallel) + dinv + x' = bf16(dinv * x) --------
__global__ __launch_bounds__(256) void rx_k(const int* __restrict__ rp,
                                            const uint2* __restrict__ ep,
                                            const float* __restrict__ x,
                                            float* __restrict__ dinv,
                                            __hip_bfloat16* __restrict__ xbf) {
    int n = (blockIdx.x * 256 + threadIdx.x) >> 6;
    int lane = threadIdx.x & 63;
    int beg = rp[n], end = rp[n + 1];
    float s = 0.f;
    for (int i = beg + lane; i < end; i += 64)
        s += __uint_as_float(ep[i].y);
#pragma unroll
    for (int off = 32; off > 0; off >>= 1) s += __shfl_xor(s, off, 64);
    float d = rsqrtf(s + 1.0f);  // + self-loop
    if (lane == 0) dinv[n] = d;
    float2 v = *(const float2*)(x + (size_t)n * 128 + lane * 2);
    alignas(4) __hip_bfloat16 o[2] = {__float2bfloat16(d * v.x),
                                      __float2bfloat16(d * v.y)};
    *(unsigned int*)((unsigned short*)xbf + (size_t)n * 128 + lane * 2) =
        *(const unsigned int*)o;
}

// ---------------- FUSED gather SpMM + h2 GEMM ---------------------------------
// Block = 16 consecutive nodes (one MFMA row-tile). Wave w gathers nodes
// base+w*4+s (8-deep ILP) into LDS y-tile[16][128] bf16 (16B-slot swizzle
// slot ^= (row&3)<<2 -> conflict-free frag reads). One barrier, then
// h2[16x512] = tanh(ytile @ WT^T + bg) via 4 K-steps x 8 col-frags; B-frags
// from packed WTpk (coalesced 1KB bursts, L2-hot); permuted V write.
// Eliminates the ybf round-trip and the separate h2 dispatch.
__global__ __launch_bounds__(256) void gh2_k(
    const int* __restrict__ rp, const uint2* __restrict__ ep,
    const unsigned short* __restrict__ xbf, const float* __restrict__ dinv,
    const __hip_bfloat16* __restrict__ WTpk, const float* __restrict__ bg,
    __hip_bfloat16* __restrict__ V) {
    __shared__ char yt[4096];  // [16 rows][256 B], swizzled 16B slots
    const int tid = threadIdx.x;
    const int lane = tid & 63, wid = tid >> 6;
    const int base = blockIdx.x * 16;

    // ---- gather: 4 nodes per wave ----
    for (int s = 0; s < 4; ++s) {
        int n = base + wid * 4 + s;
        int beg = rp[n], end = rp[n + 1];
        float accx, accy;
        {
            unsigned int u = *(const unsigned int*)(xbf + (size_t)n * 128 + lane * 2);
            accx = bf2f((unsigned short)(u & 0xffff));
            accy = bf2f((unsigned short)(u >> 16));
        }
        int i = beg;
        for (; i + 8 <= end; i += 8) {
            uint2 p[8];
            unsigned int u[8];
#pragma unroll
            for (int k = 0; k < 8; ++k) p[k] = ep[i + k];
#pragma unroll
            for (int k = 0; k < 8; ++k)
                u[k] = *(const unsigned int*)(xbf + (size_t)p[k].x * 128 + lane * 2);
#pragma unroll
            for (int k = 0; k < 8; ++k) {
                float c = __uint_as_float(p[k].y);
                accx += c * bf2f((unsigned short)(u[k] & 0xffff));
                accy += c * bf2f((unsigned short)(u[k] >> 16));
            }
        }
        for (; i + 4 <= end; i += 4) {
            uint2 p[4];
            unsigned int u[4];
#pragma unroll
            for (int k = 0; k < 4; ++k) p[k] = ep[i + k];
#pragma unroll
            for (int k = 0; k < 4; ++k)
                u[k] = *(const unsigned int*)(xbf + (size_t)p[k].x * 128 + lane * 2);
#pragma unroll
            for (int k = 0; k < 4; ++k) {
                float c = __uint_as_float(p[k].y);
                accx += c * bf2f((unsigned short)(u[k] & 0xffff));
                accy += c * bf2f((unsigned short)(u[k] >> 16));
            }
        }
        for (; i < end; ++i) {
            uint2 p = ep[i];
            unsigned int u = *(const unsigned int*)(xbf + (size_t)p.x * 128 + lane * 2);
            float c = __uint_as_float(p.y);
            accx += c * bf2f((unsigned short)(u & 0xffff));
            accy += c * bf2f((unsigned short)(u >> 16));
        }
        float dn = dinv[n];
        int r = wid * 4 + s;
        int p = (lane >> 2) ^ ((r & 3) << 2);  // physical 16B slot
        unsigned int o = (unsigned int)f2bf(accx * dn) |
                         ((unsigned int)f2bf(accy * dn) << 16);
        *(unsigned int*)(yt + r * 256 + p * 16 + (lane & 3) * 4) = o;
    }
    __syncthreads();

    // ---- h2: out[16 x 512]; wave w -> cols w*128..+127 (8 frags) ----
    const int l15 = lane & 15, lhi = lane >> 4;
    const int ar3 = (l15 & 3) << 2;
    f32x4 acc[8] = {};
#pragma unroll
    for (int kt = 0; kt < 4; ++kt) {
        bf16x8 af = *(const bf16x8*)(yt + l15 * 256 + (((kt * 4 + lhi) ^ ar3) << 4));
        bf16x8 bfr[8];
#pragma unroll
        for (int j = 0; j < 8; ++j)
            bfr[j] = *(const bf16x8*)(WTpk +
                ((size_t)((wid * 8 + j) * 4 + kt) * 64 + lane) * 8);
#pragma unroll
        for (int j = 0; j < 8; ++j)
            acc[j] = __builtin_amdgcn_mfma_f32_16x16x32_bf16(
                bfr[j], af, acc[j], 0, 0, 0);  // SWAPPED operands
    }
    // epilogue: m = base + l15 ; n = wid*128 + j*16 + lhi*4 + r2 ; permute write
    int m = base + l15;
    size_t rowbase = ((size_t)(((m >> 7) << 5) | (m & 31))) * 2048 +
                     (size_t)(((m >> 5) & 3) * 512);
#pragma unroll
    for (int j = 0; j < 8; ++j) {
        int n = wid * 128 + j * 16 + lhi * 4;
        float4 bv = *(const float4*)(bg + n);
        ushort4 o;
#pragma unroll
        for (int r2 = 0; r2 < 4; ++r2) {
            float v = acc[j][r2] + ((const float*)&bv)[r2];
            v = 1.0f - 2.0f / (__expf(2.0f * v) + 1.0f);  // tanh
            ((unsigned short*)&o)[r2] = f2bf(v);
        }
        *(ushort4*)((unsigned short*)V + rowbase + n) = o;
    }
}

// ---------------- async global -> LDS, 16B per lane ---------------------------
__device__ __forceinline__ void gll16(const void* g, void* l) {
    __builtin_amdgcn_global_load_lds(
        (const __attribute__((address_space(1))) void*)g,
        (__attribute__((address_space(3))) void*)l, 16, 0, 0);
}

// ---------------- bf16 MFMA GEMM (128x128): 4-buffer, 3-deep prefetch ---------
// Used for cnn1 and cnn2+final. Accepted structure-class limit for cnn1.
template <int ACT, int OUT_MODE, int SWIZ_NTX>
__global__ __launch_bounds__(256) void gemm_mfma_k(
    const __hip_bfloat16* __restrict__ A, const __hip_bfloat16* __restrict__ B,
    const float* __restrict__ bias, void* __restrict__ Cout,
    const float* __restrict__ wlin, int M, int N, int K) {
    __shared__ char lds[65536];  // 4 bufs x (A 8KB | B 8KB)

    const int tid = threadIdx.x;
    const int lane = tid & 63, wid = tid >> 6;
    int bx, by;
    if (SWIZ_NTX > 0) {
        int orig = blockIdx.x;
        int per = gridDim.x / (8 * SWIZ_NTX);
        int xcd = orig & 7, k = orig >> 3;
        by = xcd * per + k / SWIZ_NTX;
        bx = k % SWIZ_NTX;
    } else {
        bx = blockIdx.x;
        by = blockIdx.y;
    }
    const int bm = by * 128, bn = bx * 128;
    const int wr = wid >> 1, wc = wid & 1;

    const int srow = wid * 16 + (lane >> 2);
    const int skcol = (((lane & 3) ^ ((lane >> 3) & 3))) * 8;
    const __hip_bfloat16* Abase = A + (size_t)(bm + srow) * K + skcol;
    const __hip_bfloat16* Bbase = B + (size_t)(bn + srow) * K + skcol;
    const int ldso = wid * 1024;

    f32x4 acc[4][4] = {};

    const int lrow = lane & 15;
    const int lkb = (((lane >> 4) ^ ((lane >> 1) & 3)) << 4);
    const int nk = K >> 5;

    auto stage = [&](int buf, int kt) {
        char* la = lds + buf * 16384;
        char* lb = la + 8192;
        gll16(Abase + kt * 32,                  la + ldso);
        gll16(Abase + kt * 32 + (size_t)64 * K, la + 4096 + ldso);
        gll16(Bbase + kt * 32,                  lb + ldso);
        gll16(Bbase + kt * 32 + (size_t)64 * K, lb + 4096 + ldso);
    };

    stage(0, 0);
    stage(1, 1);
    stage(2, 2);

    for (int kt = 0; kt < nk; ++kt) {
        int ahead = nk - 1 - kt;
        if (ahead >= 2)      asm volatile("s_waitcnt vmcnt(8)" ::: "memory");
        else if (ahead == 1) asm volatile("s_waitcnt vmcnt(4)" ::: "memory");
        else                 asm volatile("s_waitcnt vmcnt(0)" ::: "memory");
        __builtin_amdgcn_s_barrier();
        asm volatile("" ::: "memory");
        if (kt + 3 < nk) stage((kt + 3) & 3, kt + 3);

        const char* la = lds + (kt & 3) * 16384;
        const char* lb = la + 8192;
        bf16x8 af[4], bfr[4];
#pragma unroll
        for (int i = 0; i < 4; ++i)
            af[i] = *(const bf16x8*)(la + (wr * 64 + i * 16 + lrow) * 64 + lkb);
#pragma unroll
        for (int j = 0; j < 4; ++j)
            bfr[j] = *(const bf16x8*)(lb + (wc * 64 + j * 16 + lrow) * 64 + lkb);
        __builtin_amdgcn_s_setprio(1);
#pragma unroll
        for (int i = 0; i < 4; ++i)
#pragma unroll
            for (int j = 0; j < 4; ++j)
                acc[i][j] = __builtin_amdgcn_mfma_f32_16x16x32_bf16(
                    bfr[j], af[i], acc[i][j], 0, 0, 0);  // SWAPPED operands
        __builtin_amdgcn_s_setprio(0);
        asm volatile("" ::: "memory");
    }

    const int l15 = lane & 15, lhi = lane >> 4;

    if (OUT_MODE == 3) {
        float p0 = 0.f, p1 = 0.f;
#pragma unroll
        for (int i = 0; i < 4; ++i) {
            int e = (i & 1) * 16 + l15;  // m & 31
#pragma unroll
            for (int j = 0; j < 4; ++j) {
                int n = bn + wc * 64 + j * 16 + lhi * 4;
                float4 bv = *(const float4*)(bias + n);
#pragma unroll
                for (int r = 0; r < 4; ++r) {
                    float v = fmaxf(acc[i][j][r] + ((const float*)&bv)[r], 0.f);
                    float wl = wlin[(n + r) * 32 + e];
                    if (i < 2) p0 += v * wl; else p1 += v * wl;
                }
            }
        }
#pragma unroll
        for (int off = 32; off > 0; off >>= 1) {
            p0 += __shfl_down(p0, off, 64);
            p1 += __shfl_down(p1, off, 64);
        }
        if (lane == 0) {
            int g = (bm >> 5) + wr * 2;
            atomicAdd(&((float*)Cout)[g], p0);
            atomicAdd(&((float*)Cout)[g + 1], p1);
        }
        return;
    }

#pragma unroll
    for (int i = 0; i < 4; ++i) {
        int m = bm + wr * 64 + i * 16 + l15;
#pragma unroll
        for (int j = 0; j < 4; ++j) {
            int n = bn + wc * 64 + j * 16 + lhi * 4;
            float4 bv = *(const float4*)(bias + n);
            ushort4 o;
#pragma unroll
            for (int r = 0; r < 4; ++r) {
                float v = acc[i][j][r] + ((const float*)&bv)[r];
                if (ACT == 1) v = fmaxf(v, 0.f);
                ((unsigned short*)&o)[r] = f2bf(v);
            }
            *(ushort4*)((unsigned short*)Cout + (size_t)m * N + n) = o;
        }
    }
}

// ---------------- sigmoid over 512 graph logits --------------------------------
__global__ void sigmoid_k(const float* __restrict__ logits,
                          const float* __restrict__ blin, float* __restrict__ out) {
    int b = blockIdx.x * 256 + threadIdx.x;
    out[b] = 1.0f / (1.0f + expf(-(logits[b] + blin[0])));
}

extern "C" void kernel_launch(void* const* d_in, const int* in_sizes, int n_in,
                              void* d_out, int out_size, void* d_ws, size_t ws_size,
                              hipStream_t stream) {
    const float* x    = (const float*)d_in[0];
    const float* eattr= (const float*)d_in[1];
    const float* w1   = (const float*)d_in[2];
    const float* wg   = (const float*)d_in[3];
    const float* bg   = (const float*)d_in[4];
    const float* wc1  = (const float*)d_in[5];
    const float* bc1  = (const float*)d_in[6];
    const float* wc2  = (const float*)d_in[7];
    const float* bc2  = (const float*)d_in[8];
    const float* wlin = (const float*)d_in[9];
    const float* blin = (const float*)d_in[10];
    const int*   ei   = (const int*)d_in[11];
    const int* esrc = ei;
    const int* edst = ei + N_EDGES;
    float* out = (float*)d_out;

    // workspace layout (bytes, 16B aligned)
    char* ws = (char*)d_ws;
    float*          dinv   = (float*)(ws + 0);          // 262144
    int*            cnt    = (int*)(ws + 262144);       // 262144
    int*            rp     = (int*)(ws + 524288);       // 262160 (65537 ints)
    int*            cursor = (int*)(ws + 786688);       // 262144
    uint2*          ep     = (uint2*)(ws + 1048832);    // 4194304 (packed src,w)
    __hip_bfloat16* WTpk   = (__hip_bfloat16*)(ws + 5243136);   // 131072
    __hip_bfloat16* V      = (__hip_bfloat16*)(ws + 22151424);  // 67108864
    __hip_bfloat16* act1   = (__hip_bfloat16*)(ws + 89260288);  // 16777216
    __hip_bfloat16* wc1bf  = (__hip_bfloat16*)(ws + 106037504); // 2097152
    __hip_bfloat16* wc2bf  = (__hip_bfloat16*)(ws + 108134656); // 262144
    __hip_bfloat16* xbf    = (__hip_bfloat16*)(ws + 108396800); // 16777216
    float*          logits = (float*)(ws + 125174016);  // 2048
    int*            bsum   = (int*)(ws + 125176064);    // 1024
    if (ws_size < (size_t)125177088) return;

    // 1) init (cnt=0, logits=0)
    init_k<<<N_NODES / 256, 256, 0, stream>>>(cnt, logits);

    // 2) merged: in-degree counts + weight prep (wc1/wc2 bf16, W_comb packed)
    prep1_k<<<3456, 256, 0, stream>>>(edst, cnt, wc1, wc1bf, wc2, wc2bf,
                                      w1, wg, WTpk);

    // 3) hierarchical scan -> rp, cursor
    scan1_k<<<256, 256, 0, stream>>>(cnt, rp, bsum);
    scan2_k<<<1, 256, 0, stream>>>(bsum, rp);
    scan3_k<<<256, 256, 0, stream>>>(rp, bsum, cursor);

    // 4) scatter edges into CSR, packed (src, w) 8B records
    scatter_k<<<N_EDGES / 256, 256, 0, stream>>>(esrc, edst, eattr, cursor, ep);

    // 5) fused degree row-sum + dinv + x' = bf16(dinv*x)
    rx_k<<<N_NODES / 4, 256, 0, stream>>>(rp, ep, x, dinv, xbf);

    // 6) FUSED gather SpMM + h2 GEMM -> V (permuted bf16); no ybf round-trip
    gh2_k<<<N_NODES / 16, 256, 0, stream>>>(rp, ep, (const unsigned short*)xbf,
                                            dinv, WTpk, bg, V);

    // 7) cnn1: act1 = relu(V @ wc1^T + bc1), XCD-swizzled 1D grid
    gemm_mfma_k<1, 1, 4><<<512, 256, 0, stream>>>(
        V, wc1bf, bc1, act1, nullptr, 16384, 512, 2048);

    // 8) cnn2 + final dot fused
    gemm_mfma_k<1, 3, 0><<<dim3(2, 128), 256, 0, stream>>>(
        act1, wc2bf, bc2, logits, wlin, 16384, 256, 512);

    // 9) sigmoid
    sigmoid_k<<<2, 256, 0, stream>>>(logits, blin, out);
}

// Round 18
// 210.269 us; speedup vs baseline: 1.0403x; 1.0403x over previous
//
#include <hip/hip_runtime.h>
#include <hip/hip_bf16.h>

#define N_NODES 65536
#define N_EDGES 524288

typedef __attribute__((ext_vector_type(8))) short bf16x8;
typedef __attribute__((ext_vector_type(4))) float f32x4;

__device__ __forceinline__ float bf2f(unsigned short u) {
    union { unsigned int i; float f; } v;
    v.i = ((unsigned int)u) << 16;
    return v.f;
}
__device__ __forceinline__ unsigned short f2bf(float f) {
    union { float f; unsigned int i; } v;
    v.f = f;
    unsigned int r = v.i + 0x7fff + ((v.i >> 16) & 1);  // round-to-nearest-even
    return (unsigned short)(r >> 16);
}

// ---------------- init: cnt=0, logits=0 ---------------------------------------
__global__ void init_k(int* __restrict__ cnt, float* __restrict__ logits) {
    int i = blockIdx.x * 256 + threadIdx.x;
    cnt[i] = 0;
    if (i < 512) logits[i] = 0.0f;
}
__global__ void cnt_k(const int* __restrict__ dst, int* __restrict__ cnt) {
    int e = blockIdx.x * 256 + threadIdx.x;
    atomicAdd(&cnt[dst[e]], 1);
}

// ------- hierarchical exclusive scan of cnt[65536] -> rp, cursor --------------
__global__ __launch_bounds__(256) void scan1_k(const int* __restrict__ cnt,
                                               int* __restrict__ rp,
                                               int* __restrict__ bsum) {
    __shared__ int s[256];
    int t = threadIdx.x, g = blockIdx.x * 256 + t;
    int v = cnt[g];
    s[t] = v;
    __syncthreads();
    for (int d = 1; d < 256; d <<= 1) {
        int u = (t >= d) ? s[t - d] : 0;
        __syncthreads();
        s[t] += u;
        __syncthreads();
    }
    rp[g] = s[t] - v;
    if (t == 255) bsum[blockIdx.x] = s[255];
}
__global__ __launch_bounds__(256) void scan2_k(int* __restrict__ bsum,
                                               int* __restrict__ rp) {
    __shared__ int s[256];
    int t = threadIdx.x;
    int v = bsum[t];
    s[t] = v;
    __syncthreads();
    for (int d = 1; d < 256; d <<= 1) {
        int u = (t >= d) ? s[t - d] : 0;
        __syncthreads();
        s[t] += u;
        __syncthreads();
    }
    bsum[t] = s[t] - v;
    if (t == 255) rp[65536] = s[255];
}
__global__ __launch_bounds__(256) void scan3_k(int* __restrict__ rp,
                                               const int* __restrict__ bsum,
                                               int* __restrict__ cursor) {
    int t = threadIdx.x, g = blockIdx.x * 256 + t;
    int r = rp[g] + bsum[blockIdx.x];
    rp[g] = r;
    cursor[g] = r;
}

// ------- scatter edges into dst-sorted CSR order, packed (src, w) -------------
__global__ void scatter_k(const int* __restrict__ src, const int* __restrict__ dst,
                          const float* __restrict__ w,
                          int* __restrict__ cursor, uint2* __restrict__ ep) {
    int e = blockIdx.x * 256 + threadIdx.x;
    int pos = atomicAdd(&cursor[dst[e]], 1);
    uint2 p;
    p.x = (unsigned int)src[e];
    p.y = __float_as_uint(w[e]);
    ep[pos] = p;
}

// ------- degree from CSR row-sum (coalesced, no atomics) + dinv ---------------
__global__ void rowsum_k(const int* __restrict__ rp, const uint2* __restrict__ ep,
                         float* __restrict__ dinv) {
    int n = blockIdx.x * 256 + threadIdx.x;
    int beg = rp[n], end = rp[n + 1];
    float s = 1.0f;  // self-loop weight
    for (int i = beg; i < end; ++i) s += __uint_as_float(ep[i].y);
    dinv[n] = rsqrtf(s);
}

// ------- x' = bf16(dinv[row] * x) ---------------------------------------------
__global__ void xscale_k(const float* __restrict__ x, const float* __restrict__ dinv,
                         __hip_bfloat16* __restrict__ xbf) {
    int i = (blockIdx.x * 256 + threadIdx.x) * 4;
    float d = dinv[i >> 7];
    float4 v = *(const float4*)(x + i);
    alignas(8) __hip_bfloat16 tmp[4] = {
        __float2bfloat16(d * v.x), __float2bfloat16(d * v.y),
        __float2bfloat16(d * v.z), __float2bfloat16(d * v.w)};
    *(ushort4*)((unsigned short*)xbf + i) = *(const ushort4*)tmp;
}

// ------- weight prep: PACK(wc1) | f2b(wc2) | wcomb row-major ------------------
// wc1 packed fragment order (nkt=64):
//   wc1pk[((nb*64 + kt)*64 + l)*8 + ke] = wc1[nb*16+(l&15)][kt*32+(l>>4)*8+ke]
// blocks [0,512): wc1 pack ; [512,640): wc2 f2b ; [640,896): wcomb
__global__ void wprep_k(const float* __restrict__ wc1, __hip_bfloat16* __restrict__ wc1pk,
                        const float* __restrict__ wc2, __hip_bfloat16* __restrict__ wc2bf,
                        const float* __restrict__ w1, const float* __restrict__ wg,
                        __hip_bfloat16* __restrict__ WT) {
    int bid = blockIdx.x;
    if (bid < 512) {
        int t = bid * 256 + threadIdx.x;  // [0, 131072)
        int l = t & 63, grp = t >> 6;
        int kt = grp & 63, nb = grp >> 6;
        int n = nb * 16 + (l & 15);
        int k0 = kt * 32 + (l >> 4) * 8;
        const float* src = wc1 + (size_t)n * 2048 + k0;
        alignas(16) __hip_bfloat16 tmp[8];
#pragma unroll
        for (int e = 0; e < 8; ++e) tmp[e] = __float2bfloat16(src[e]);
        *(ushort4*)((unsigned short*)wc1pk + (size_t)t * 8)     = *(const ushort4*)tmp;
        *(ushort4*)((unsigned short*)wc1pk + (size_t)t * 8 + 4) = *(const ushort4*)(tmp + 4);
    } else if (bid < 640) {
        int i = (bid - 512) * 1024 + threadIdx.x * 4;
        float4 v = *(const float4*)(wc2 + i);
        alignas(8) __hip_bfloat16 tmp[4] = {__float2bfloat16(v.x), __float2bfloat16(v.y),
                                            __float2bfloat16(v.z), __float2bfloat16(v.w)};
        *(ushort4*)((unsigned short*)wc2bf + i) = *(const ushort4*)tmp;
    } else {
        int t = (bid - 640) * 256 + threadIdx.x;  // 512*128
        int f = t >> 7, c = t & 127;
        float s = 0.f;
#pragma unroll 8
        for (int m = 0; m < 128; ++m) s += w1[c * 128 + m] * wg[m * 512 + f];
        WT[t] = __float2bfloat16(s);  // WT[f*128 + c]
    }
}

// ---------------- gather SpMM, 8-deep ILP pipeline -----------------------------
__global__ __launch_bounds__(256) void gather_k(const int* __restrict__ rp,
                                                const uint2* __restrict__ ep,
                                                const unsigned short* __restrict__ xbf,
                                                const float* __restrict__ dinv,
                                                __hip_bfloat16* __restrict__ ybf) {
    int n = (blockIdx.x * 256 + threadIdx.x) >> 6;
    int lane = threadIdx.x & 63;
    int beg = rp[n], end = rp[n + 1];
    float accx, accy;
    {
        unsigned int u = *(const unsigned int*)(xbf + (size_t)n * 128 + lane * 2);
        accx = bf2f((unsigned short)(u & 0xffff));
        accy = bf2f((unsigned short)(u >> 16));
    }
    int i = beg;
    for (; i + 8 <= end; i += 8) {
        uint2 p[8];
        unsigned int u[8];
#pragma unroll
        for (int k = 0; k < 8; ++k) p[k] = ep[i + k];
#pragma unroll
        for (int k = 0; k < 8; ++k)
            u[k] = *(const unsigned int*)(xbf + (size_t)p[k].x * 128 + lane * 2);
#pragma unroll
        for (int k = 0; k < 8; ++k) {
            float c = __uint_as_float(p[k].y);
            accx += c * bf2f((unsigned short)(u[k] & 0xffff));
            accy += c * bf2f((unsigned short)(u[k] >> 16));
        }
    }
    for (; i + 4 <= end; i += 4) {
        uint2 p[4];
        unsigned int u[4];
#pragma unroll
        for (int k = 0; k < 4; ++k) p[k] = ep[i + k];
#pragma unroll
        for (int k = 0; k < 4; ++k)
            u[k] = *(const unsigned int*)(xbf + (size_t)p[k].x * 128 + lane * 2);
#pragma unroll
        for (int k = 0; k < 4; ++k) {
            float c = __uint_as_float(p[k].y);
            accx += c * bf2f((unsigned short)(u[k] & 0xffff));
            accy += c * bf2f((unsigned short)(u[k] >> 16));
        }
    }
    for (; i < end; ++i) {
        uint2 p = ep[i];
        unsigned int u = *(const unsigned int*)(xbf + (size_t)p.x * 128 + lane * 2);
        float c = __uint_as_float(p.y);
        accx += c * bf2f((unsigned short)(u & 0xffff));
        accy += c * bf2f((unsigned short)(u >> 16));
    }
    float dn = dinv[n];
    accx *= dn;
    accy *= dn;
    alignas(4) __hip_bfloat16 o[2] = {__float2bfloat16(accx), __float2bfloat16(accy)};
    *(unsigned int*)((unsigned short*)ybf + (size_t)n * 128 + lane * 2) =
        *(const unsigned int*)o;
}

// ---------------- async global -> LDS, 16B per lane ---------------------------
__device__ __forceinline__ void gll16(const void* g, void* l) {
    __builtin_amdgcn_global_load_lds(
        (const __attribute__((address_space(1))) void*)g,
        (__attribute__((address_space(3))) void*)l, 16, 0, 0);
}

// ---------------- bf16 MFMA GEMM (128x128): 4-buffer, 3-deep prefetch ---------
// Used for h2 (OUT_MODE 2) and cnn2+final (OUT_MODE 3). R15-verbatim.
template <int ACT, int OUT_MODE, int SWIZ_NTX>
__global__ __launch_bounds__(256) void gemm_mfma_k(
    const __hip_bfloat16* __restrict__ A, const __hip_bfloat16* __restrict__ B,
    const float* __restrict__ bias, void* __restrict__ Cout,
    const float* __restrict__ wlin, int M, int N, int K) {
    __shared__ char lds[65536];  // 4 bufs x (A 8KB | B 8KB)

    const int tid = threadIdx.x;
    const int lane = tid & 63, wid = tid >> 6;
    int bx, by;
    if (SWIZ_NTX > 0) {
        int orig = blockIdx.x;
        int per = gridDim.x / (8 * SWIZ_NTX);
        int xcd = orig & 7, k = orig >> 3;
        by = xcd * per + k / SWIZ_NTX;
        bx = k % SWIZ_NTX;
    } else {
        bx = blockIdx.x;
        by = blockIdx.y;
    }
    const int bm = by * 128, bn = bx * 128;
    const int wr = wid >> 1, wc = wid & 1;

    const int srow = wid * 16 + (lane >> 2);
    const int skcol = (((lane & 3) ^ ((lane >> 3) & 3))) * 8;
    const __hip_bfloat16* Abase = A + (size_t)(bm + srow) * K + skcol;
    const __hip_bfloat16* Bbase = B + (size_t)(bn + srow) * K + skcol;
    const int ldso = wid * 1024;

    f32x4 acc[4][4] = {};

    const int lrow = lane & 15;
    const int lkb = (((lane >> 4) ^ ((lane >> 1) & 3)) << 4);
    const int nk = K >> 5;

    auto stage = [&](int buf, int kt) {
        char* la = lds + buf * 16384;
        char* lb = la + 8192;
        gll16(Abase + kt * 32,                  la + ldso);
        gll16(Abase + kt * 32 + (size_t)64 * K, la + 4096 + ldso);
        gll16(Bbase + kt * 32,                  lb + ldso);
        gll16(Bbase + kt * 32 + (size_t)64 * K, lb + 4096 + ldso);
    };

    stage(0, 0);
    stage(1, 1);
    stage(2, 2);

    for (int kt = 0; kt < nk; ++kt) {
        int ahead = nk - 1 - kt;
        if (ahead >= 2)      asm volatile("s_waitcnt vmcnt(8)" ::: "memory");
        else if (ahead == 1) asm volatile("s_waitcnt vmcnt(4)" ::: "memory");
        else                 asm volatile("s_waitcnt vmcnt(0)" ::: "memory");
        __builtin_amdgcn_s_barrier();
        asm volatile("" ::: "memory");
        if (kt + 3 < nk) stage((kt + 3) & 3, kt + 3);

        const char* la = lds + (kt & 3) * 16384;
        const char* lb = la + 8192;
        bf16x8 af[4], bfr[4];
#pragma unroll
        for (int i = 0; i < 4; ++i)
            af[i] = *(const bf16x8*)(la + (wr * 64 + i * 16 + lrow) * 64 + lkb);
#pragma unroll
        for (int j = 0; j < 4; ++j)
            bfr[j] = *(const bf16x8*)(lb + (wc * 64 + j * 16 + lrow) * 64 + lkb);
        __builtin_amdgcn_s_setprio(1);
#pragma unroll
        for (int i = 0; i < 4; ++i)
#pragma unroll
            for (int j = 0; j < 4; ++j)
                acc[i][j] = __builtin_amdgcn_mfma_f32_16x16x32_bf16(
                    bfr[j], af[i], acc[i][j], 0, 0, 0);  // SWAPPED operands
        __builtin_amdgcn_s_setprio(0);
        asm volatile("" ::: "memory");
    }

    const int l15 = lane & 15, lhi = lane >> 4;

    if (OUT_MODE == 3) {
        float p0 = 0.f, p1 = 0.f;
#pragma unroll
        for (int i = 0; i < 4; ++i) {
            int e = (i & 1) * 16 + l15;  // m & 31
#pragma unroll
            for (int j = 0; j < 4; ++j) {
                int n = bn + wc * 64 + j * 16 + lhi * 4;
                float4 bv = *(const float4*)(bias + n);
#pragma unroll
                for (int r = 0; r < 4; ++r) {
                    float v = fmaxf(acc[i][j][r] + ((const float*)&bv)[r], 0.f);
                    float wl = wlin[(n + r) * 32 + e];
                    if (i < 2) p0 += v * wl; else p1 += v * wl;
                }
            }
        }
#pragma unroll
        for (int off = 32; off > 0; off >>= 1) {
            p0 += __shfl_down(p0, off, 64);
            p1 += __shfl_down(p1, off, 64);
        }
        if (lane == 0) {
            int g = (bm >> 5) + wr * 2;
            atomicAdd(&((float*)Cout)[g], p0);
            atomicAdd(&((float*)Cout)[g + 1], p1);
        }
        return;
    }

#pragma unroll
    for (int i = 0; i < 4; ++i) {
        int m = bm + wr * 64 + i * 16 + l15;
#pragma unroll
        for (int j = 0; j < 4; ++j) {
            int n = bn + wc * 64 + j * 16 + lhi * 4;
            float4 bv = *(const float4*)(bias + n);
            ushort4 o;
#pragma unroll
            for (int r = 0; r < 4; ++r) {
                float v = acc[i][j][r] + ((const float*)&bv)[r];
                if (ACT == 1) v = fmaxf(v, 0.f);
                if (ACT == 2) v = 1.0f - 2.0f / (__expf(2.0f * v) + 1.0f);
                ((unsigned short*)&o)[r] = f2bf(v);
            }
            if (OUT_MODE == 1) {
                *(ushort4*)((unsigned short*)Cout + (size_t)m * N + n) = o;
            } else {
                size_t prow = (size_t)(((m >> 7) << 5) | (m & 31));
                size_t idx = prow * 2048 + (size_t)(((m >> 5) & 3) * 512 + n);
                *(ushort4*)((unsigned short*)Cout + idx) = o;
            }
        }
    }
}

// ---------------- cnn1 WIDE: BM=64, BN=512 (full width), 8 waves --------------
// Traffic-minimal geometry: each V row read ONCE (A-traffic 268->67 MB); B =
// wc1 packed (2MB, L2-resident) as coalesced 1KB register bursts (R13/R14
// path). Waves 0-3 stage the 4KB A-tile (validated swizzle); all 8 waves load
// their own B frags. Wave-group counted vmcnt (queue-simulated):
//   stagers:    even 5 (tail 4), odd 5 (tail 0)
//   non-stagers: even 4,         odd 4 (tail 0)
// One barrier per K-step half; 4 A-buffers make WAR safe.
__global__ __launch_bounds__(512) void cnn1w_k(
    const __hip_bfloat16* __restrict__ A,    // V: 16384 x 2048
    const __hip_bfloat16* __restrict__ Bpk,  // wc1 packed
    const float* __restrict__ bias,
    __hip_bfloat16* __restrict__ C) {        // act1: 16384 x 512
    __shared__ char lds[16384];  // 4 bufs x 4KB A-tile
    const int tid = threadIdx.x;
    const int lane = tid & 63, wid = tid >> 6;
    const int bm = blockIdx.x * 64;
    const int K = 2048, nk = 64;
    const bool stager = (wid < 4);

    const int srow = (wid & 3) * 16 + (lane >> 2);
    const int skcol = (((lane & 3) ^ ((lane >> 3) & 3))) * 8;
    const __hip_bfloat16* Abase = A + (size_t)(bm + srow) * K + skcol;
    const int ldso = (wid & 3) * 1024;

    const __hip_bfloat16* Bp[4];
#pragma unroll
    for (int j = 0; j < 4; ++j)
        Bp[j] = Bpk + ((size_t)(wid * 4 + j) * nk) * 512 + lane * 8;

    f32x4 acc[4][4] = {};
    const int lrow = lane & 15;
    const int lkb = (((lane >> 4) ^ ((lane >> 1) & 3)) << 4);

    auto stageA = [&](int buf, int kt) {
        if (stager) gll16(Abase + kt * 32, lds + buf * 4096 + ldso);
    };

    bf16x8 b0[4], b1[4];
    stageA(0, 0);
    stageA(1, 1);
    asm volatile("" ::: "memory");
#pragma unroll
    for (int j = 0; j < 4; ++j) b0[j] = *(const bf16x8*)(Bp[j]);

#define GEMM_W(KT, BREG)                                                        \
    {                                                                           \
        const char* la = lds + ((KT) & 3) * 4096;                               \
        bf16x8 af[4];                                                           \
        _Pragma("unroll")                                                       \
        for (int i = 0; i < 4; ++i)                                             \
            af[i] = *(const bf16x8*)(la + (i * 16 + lrow) * 64 + lkb);          \
        __builtin_amdgcn_s_setprio(1);                                          \
        _Pragma("unroll")                                                       \
        for (int i = 0; i < 4; ++i)                                             \
            _Pragma("unroll")                                                   \
            for (int j = 0; j < 4; ++j)                                         \
                acc[i][j] = __builtin_amdgcn_mfma_f32_16x16x32_bf16(            \
                    BREG[j], af[i], acc[i][j], 0, 0, 0);                        \
        __builtin_amdgcn_s_setprio(0);                                          \
        asm volatile("" ::: "memory");                                          \
    }

    for (int kt = 0; kt < nk; kt += 2) {
        // ---- EVEN half: compute kt with A(kt), b0 ----
        if (kt + 2 < nk) stageA((kt + 2) & 3, kt + 2);
#pragma unroll
        for (int j = 0; j < 4; ++j)
            b1[j] = *(const bf16x8*)(Bp[j] + (size_t)(kt + 1) * 512);
        if (stager) {
            if (kt + 2 < nk) asm volatile("s_waitcnt vmcnt(5)" ::: "memory");
            else             asm volatile("s_waitcnt vmcnt(4)" ::: "memory");
        } else {
            asm volatile("s_waitcnt vmcnt(4)" ::: "memory");
        }
        __builtin_amdgcn_s_barrier();
        asm volatile("" ::: "memory");
        GEMM_W(kt, b0);

        // ---- ODD half: compute kt+1 with A(kt+1), b1 ----
        if (kt + 3 < nk) stageA((kt + 3) & 3, kt + 3);
        if (kt + 2 < nk) {
#pragma unroll
            for (int j = 0; j < 4; ++j)
                b0[j] = *(const bf16x8*)(Bp[j] + (size_t)(kt + 2) * 512);
        }
        if (kt + 2 < nk) {
            if (stager) asm volatile("s_waitcnt vmcnt(5)" ::: "memory");
            else        asm volatile("s_waitcnt vmcnt(4)" ::: "memory");
        } else {
            asm volatile("s_waitcnt vmcnt(0)" ::: "memory");
        }
        __builtin_amdgcn_s_barrier();
        asm volatile("" ::: "memory");
        GEMM_W(kt + 1, b1);
    }
#undef GEMM_W

    const int l15 = lane & 15, lhi = lane >> 4;
#pragma unroll
    for (int i = 0; i < 4; ++i) {
        int m = bm + i * 16 + l15;
#pragma unroll
        for (int j = 0; j < 4; ++j) {
            int n = wid * 64 + j * 16 + lhi * 4;
            float4 bv = *(const float4*)(bias + n);
            ushort4 o;
#pragma unroll
            for (int r = 0; r < 4; ++r) {
                float v = fmaxf(acc[i][j][r] + ((const float*)&bv)[r], 0.f);
                ((unsigned short*)&o)[r] = f2bf(v);
            }
            *(ushort4*)((unsigned short*)C + (size_t)m * 512 + n) = o;
        }
    }
}

// ---------------- sigmoid over 512 graph logits --------------------------------
__global__ void sigmoid_k(const float* __restrict__ logits,
                          const float* __restrict__ blin, float* __restrict__ out) {
    int b = blockIdx.x * 256 + threadIdx.x;
    out[b] = 1.0f / (1.0f + expf(-(logits[b] + blin[0])));
}

extern "C" void kernel_launch(void* const* d_in, const int* in_sizes, int n_in,
                              void* d_out, int out_size, void* d_ws, size_t ws_size,
                              hipStream_t stream) {
    const float* x    = (const float*)d_in[0];
    const float* eattr= (const float*)d_in[1];
    const float* w1   = (const float*)d_in[2];
    const float* wg   = (const float*)d_in[3];
    const float* bg   = (const float*)d_in[4];
    const float* wc1  = (const float*)d_in[5];
    const float* bc1  = (const float*)d_in[6];
    const float* wc2  = (const float*)d_in[7];
    const float* bc2  = (const float*)d_in[8];
    const float* wlin = (const float*)d_in[9];
    const float* blin = (const float*)d_in[10];
    const int*   ei   = (const int*)d_in[11];
    const int* esrc = ei;
    const int* edst = ei + N_EDGES;
    float* out = (float*)d_out;

    // workspace layout (bytes, 16B aligned)
    char* ws = (char*)d_ws;
    float*          dinv   = (float*)(ws + 0);          // 262144
    int*            cnt    = (int*)(ws + 262144);       // 262144
    int*            rp     = (int*)(ws + 524288);       // 262160 (65537 ints)
    int*            cursor = (int*)(ws + 786688);       // 262144
    uint2*          ep     = (uint2*)(ws + 1048832);    // 4194304 (packed src,w)
    __hip_bfloat16* WTbf   = (__hip_bfloat16*)(ws + 5243136);   // 131072
    __hip_bfloat16* ybf    = (__hip_bfloat16*)(ws + 5374208);   // 16777216
    __hip_bfloat16* V      = (__hip_bfloat16*)(ws + 22151424);  // 67108864
    __hip_bfloat16* act1   = (__hip_bfloat16*)(ws + 89260288);  // 16777216
    __hip_bfloat16* wc1pk  = (__hip_bfloat16*)(ws + 106037504); // 2097152
    __hip_bfloat16* wc2bf  = (__hip_bfloat16*)(ws + 108134656); // 262144
    __hip_bfloat16* xbf    = (__hip_bfloat16*)(ws + 108396800); // 16777216
    float*          logits = (float*)(ws + 125174016);  // 2048
    int*            bsum   = (int*)(ws + 125176064);    // 1024
    if (ws_size < (size_t)125177088) return;

    // 1) init (cnt=0, logits=0)
    init_k<<<N_NODES / 256, 256, 0, stream>>>(cnt, logits);

    // 2) in-degree counts (int atomics only)
    cnt_k<<<N_EDGES / 256, 256, 0, stream>>>(edst, cnt);

    // 3) hierarchical scan -> rp, cursor
    scan1_k<<<256, 256, 0, stream>>>(cnt, rp, bsum);
    scan2_k<<<1, 256, 0, stream>>>(bsum, rp);
    scan3_k<<<256, 256, 0, stream>>>(rp, bsum, cursor);

    // 4) scatter edges into CSR, packed (src, w) 8B records (no dinv dep)
    scatter_k<<<N_EDGES / 256, 256, 0, stream>>>(esrc, edst, eattr, cursor, ep);

    // 5) degree via coalesced CSR row-sum -> dinv
    rowsum_k<<<N_NODES / 256, 256, 0, stream>>>(rp, ep, dinv);

    // 6) weight prep (wc1 packed, wc2 bf16, W_comb) + x' = bf16(dinv * x)
    wprep_k<<<896, 256, 0, stream>>>(wc1, wc1pk, wc2, wc2bf, w1, wg, WTbf);
    xscale_k<<<(N_NODES * 128 / 4) / 256, 256, 0, stream>>>(x, dinv, xbf);

    // 7) gather SpMM (8-deep ILP) -> ybf
    gather_k<<<N_NODES / 4, 256, 0, stream>>>(rp, ep,
                                              (const unsigned short*)xbf, dinv, ybf);

    // 8) h2 = tanh(y @ W_comb + b_gcn) -> V (bf16, rearranged layout)
    gemm_mfma_k<2, 2, 0><<<dim3(4, 512), 256, 0, stream>>>(
        ybf, WTbf, bg, V, nullptr, 65536, 512, 128);

    // 9) cnn1 WIDE: act1 = relu(V @ wc1^T + bc1), full-width N, V read once
    cnn1w_k<<<256, 512, 0, stream>>>(V, wc1pk, bc1, act1);

    // 10) cnn2 + final dot fused
    gemm_mfma_k<1, 3, 0><<<dim3(2, 128), 256, 0, stream>>>(
        act1, wc2bf, bc2, logits, wlin, 16384, 256, 512);

    // 11) sigmoid
    sigmoid_k<<<2, 256, 0, stream>>>(logits, blin, out);
}

// Round 19
// 200.624 us; speedup vs baseline: 1.0903x; 1.0481x over previous
//
#include <hip/hip_runtime.h>
#include <hip/hip_bf16.h>

#define N_NODES 65536
#define N_EDGES 524288

typedef __attribute__((ext_vector_type(8))) short bf16x8;
typedef __attribute__((ext_vector_type(4))) float f32x4;

__device__ __forceinline__ float bf2f(unsigned short u) {
    union { unsigned int i; float f; } v;
    v.i = ((unsigned int)u) << 16;
    return v.f;
}
__device__ __forceinline__ unsigned short f2bf(float f) {
    union { float f; unsigned int i; } v;
    v.f = f;
    unsigned int r = v.i + 0x7fff + ((v.i >> 16) & 1);  // round-to-nearest-even
    return (unsigned short)(r >> 16);
}

// ---------------- init: cnt=0, logits=0 ---------------------------------------
__global__ void init_k(int* __restrict__ cnt, float* __restrict__ logits) {
    int i = blockIdx.x * 256 + threadIdx.x;
    cnt[i] = 0;
    if (i < 512) logits[i] = 0.0f;
}
__global__ void cnt_k(const int* __restrict__ dst, int* __restrict__ cnt) {
    int e = blockIdx.x * 256 + threadIdx.x;
    atomicAdd(&cnt[dst[e]], 1);
}

// ------- hierarchical exclusive scan of cnt[65536] -> rp, cursor --------------
__global__ __launch_bounds__(256) void scan1_k(const int* __restrict__ cnt,
                                               int* __restrict__ rp,
                                               int* __restrict__ bsum) {
    __shared__ int s[256];
    int t = threadIdx.x, g = blockIdx.x * 256 + t;
    int v = cnt[g];
    s[t] = v;
    __syncthreads();
    for (int d = 1; d < 256; d <<= 1) {
        int u = (t >= d) ? s[t - d] : 0;
        __syncthreads();
        s[t] += u;
        __syncthreads();
    }
    rp[g] = s[t] - v;
    if (t == 255) bsum[blockIdx.x] = s[255];
}
__global__ __launch_bounds__(256) void scan2_k(int* __restrict__ bsum,
                                               int* __restrict__ rp) {
    __shared__ int s[256];
    int t = threadIdx.x;
    int v = bsum[t];
    s[t] = v;
    __syncthreads();
    for (int d = 1; d < 256; d <<= 1) {
        int u = (t >= d) ? s[t - d] : 0;
        __syncthreads();
        s[t] += u;
        __syncthreads();
    }
    bsum[t] = s[t] - v;
    if (t == 255) rp[65536] = s[255];
}
__global__ __launch_bounds__(256) void scan3_k(int* __restrict__ rp,
                                               const int* __restrict__ bsum,
                                               int* __restrict__ cursor) {
    int t = threadIdx.x, g = blockIdx.x * 256 + t;
    int r = rp[g] + bsum[blockIdx.x];
    rp[g] = r;
    cursor[g] = r;
}

// ------- scatter edges into dst-sorted CSR order, packed (src, w) -------------
__global__ void scatter_k(const int* __restrict__ src, const int* __restrict__ dst,
                          const float* __restrict__ w,
                          int* __restrict__ cursor, uint2* __restrict__ ep) {
    int e = blockIdx.x * 256 + threadIdx.x;
    int pos = atomicAdd(&cursor[dst[e]], 1);
    uint2 p;
    p.x = (unsigned int)src[e];
    p.y = __float_as_uint(w[e]);
    ep[pos] = p;
}

// ------- degree from CSR row-sum (coalesced, no atomics) + dinv ---------------
__global__ void rowsum_k(const int* __restrict__ rp, const uint2* __restrict__ ep,
                         float* __restrict__ dinv) {
    int n = blockIdx.x * 256 + threadIdx.x;
    int beg = rp[n], end = rp[n + 1];
    float s = 1.0f;  // self-loop weight
    for (int i = beg; i < end; ++i) s += __uint_as_float(ep[i].y);
    dinv[n] = rsqrtf(s);
}

// ------- x' = bf16(dinv[row] * x) ---------------------------------------------
__global__ void xscale_k(const float* __restrict__ x, const float* __restrict__ dinv,
                         __hip_bfloat16* __restrict__ xbf) {
    int i = (blockIdx.x * 256 + threadIdx.x) * 4;
    float d = dinv[i >> 7];
    float4 v = *(const float4*)(x + i);
    alignas(8) __hip_bfloat16 tmp[4] = {
        __float2bfloat16(d * v.x), __float2bfloat16(d * v.y),
        __float2bfloat16(d * v.z), __float2bfloat16(d * v.w)};
    *(ushort4*)((unsigned short*)xbf + i) = *(const ushort4*)tmp;
}

// ------- weight prep: PACK(wc1) | f2b(wc2) | wcomb PACKED ---------------------
// wc1pk (nkt=64): wc1pk[((nb*64+kt)*64+l)*8+ke] = wc1[nb*16+(l&15)][kt*32+(l>>4)*8+ke]
// WTpk  (nkt=4):  WTpk [((nb*4 +kt)*64+l)*8+ke] = WT [nb*16+(l&15)][kt*32+(l>>4)*8+ke]
// blocks [0,512): wc1 pack ; [512,640): wc2 f2b ; [640,896): wcomb packed
__global__ void wprep_k(const float* __restrict__ wc1, __hip_bfloat16* __restrict__ wc1pk,
                        const float* __restrict__ wc2, __hip_bfloat16* __restrict__ wc2bf,
                        const float* __restrict__ w1, const float* __restrict__ wg,
                        __hip_bfloat16* __restrict__ WTpk) {
    int bid = blockIdx.x;
    if (bid < 512) {
        int t = bid * 256 + threadIdx.x;  // [0, 131072)
        int l = t & 63, grp = t >> 6;
        int kt = grp & 63, nb = grp >> 6;
        int n = nb * 16 + (l & 15);
        int k0 = kt * 32 + (l >> 4) * 8;
        const float* src = wc1 + (size_t)n * 2048 + k0;
        alignas(16) __hip_bfloat16 tmp[8];
#pragma unroll
        for (int e = 0; e < 8; ++e) tmp[e] = __float2bfloat16(src[e]);
        *(ushort4*)((unsigned short*)wc1pk + (size_t)t * 8)     = *(const ushort4*)tmp;
        *(ushort4*)((unsigned short*)wc1pk + (size_t)t * 8 + 4) = *(const ushort4*)(tmp + 4);
    } else if (bid < 640) {
        int i = (bid - 512) * 1024 + threadIdx.x * 4;
        float4 v = *(const float4*)(wc2 + i);
        alignas(8) __hip_bfloat16 tmp[4] = {__float2bfloat16(v.x), __float2bfloat16(v.y),
                                            __float2bfloat16(v.z), __float2bfloat16(v.w)};
        *(ushort4*)((unsigned short*)wc2bf + i) = *(const ushort4*)tmp;
    } else {
        int t = (bid - 640) * 256 + threadIdx.x;  // 512*128
        int f = t >> 7, c = t & 127;
        float s = 0.f;
#pragma unroll 8
        for (int m = 0; m < 128; ++m) s += w1[c * 128 + m] * wg[m * 512 + f];
        // packed index (nkt = 4): validated formula from R13/R16
        int pk = ((((f >> 4) * 4 + (c >> 5)) * 64 + ((c >> 3) & 3) * 16 + (f & 15)) * 8) + (c & 7);
        WTpk[pk] = __float2bfloat16(s);
    }
}

// ---------------- gather SpMM, 8-deep ILP pipeline -----------------------------
__global__ __launch_bounds__(256) void gather_k(const int* __restrict__ rp,
                                                const uint2* __restrict__ ep,
                                                const unsigned short* __restrict__ xbf,
                                                const float* __restrict__ dinv,
                                                __hip_bfloat16* __restrict__ ybf) {
    int n = (blockIdx.x * 256 + threadIdx.x) >> 6;
    int lane = threadIdx.x & 63;
    int beg = rp[n], end = rp[n + 1];
    float accx, accy;
    {
        unsigned int u = *(const unsigned int*)(xbf + (size_t)n * 128 + lane * 2);
        accx = bf2f((unsigned short)(u & 0xffff));
        accy = bf2f((unsigned short)(u >> 16));
    }
    int i = beg;
    for (; i + 8 <= end; i += 8) {
        uint2 p[8];
        unsigned int u[8];
#pragma unroll
        for (int k = 0; k < 8; ++k) p[k] = ep[i + k];
#pragma unroll
        for (int k = 0; k < 8; ++k)
            u[k] = *(const unsigned int*)(xbf + (size_t)p[k].x * 128 + lane * 2);
#pragma unroll
        for (int k = 0; k < 8; ++k) {
            float c = __uint_as_float(p[k].y);
            accx += c * bf2f((unsigned short)(u[k] & 0xffff));
            accy += c * bf2f((unsigned short)(u[k] >> 16));
        }
    }
    for (; i + 4 <= end; i += 4) {
        uint2 p[4];
        unsigned int u[4];
#pragma unroll
        for (int k = 0; k < 4; ++k) p[k] = ep[i + k];
#pragma unroll
        for (int k = 0; k < 4; ++k)
            u[k] = *(const unsigned int*)(xbf + (size_t)p[k].x * 128 + lane * 2);
#pragma unroll
        for (int k = 0; k < 4; ++k) {
            float c = __uint_as_float(p[k].y);
            accx += c * bf2f((unsigned short)(u[k] & 0xffff));
            accy += c * bf2f((unsigned short)(u[k] >> 16));
        }
    }
    for (; i < end; ++i) {
        uint2 p = ep[i];
        unsigned int u = *(const unsigned int*)(xbf + (size_t)p.x * 128 + lane * 2);
        float c = __uint_as_float(p.y);
        accx += c * bf2f((unsigned short)(u & 0xffff));
        accy += c * bf2f((unsigned short)(u >> 16));
    }
    float dn = dinv[n];
    accx *= dn;
    accy *= dn;
    alignas(4) __hip_bfloat16 o[2] = {__float2bfloat16(accx), __float2bfloat16(accy)};
    *(unsigned int*)((unsigned short*)ybf + (size_t)n * 128 + lane * 2) =
        *(const unsigned int*)o;
}

// ---------------- async global -> LDS, 16B per lane ---------------------------
__device__ __forceinline__ void gll16(const void* g, void* l) {
    __builtin_amdgcn_global_load_lds(
        (const __attribute__((address_space(1))) void*)g,
        (__attribute__((address_space(3))) void*)l, 16, 0, 0);
}

// ---------------- FUSED h2 + cnn1: act1 = relu(tanh(y@WC+bg) @ wc1^T + bc1) ---
// Block = 64 act1 rows (2 graphs), 8 waves. For each K-segment g (512 cols of
// the virtual V = one GCN g-group):
//   1. stage y-tile[64 rows][128] (16KB LDS, gll16, pre-swizzled source)
//   2. h2 sub-GEMM (4 K-steps, WTpk packed bursts) + tanh -> ht[64][512] LDS
//   3. 16 BARRIER-FREE cnn1 K-steps: A from read-only ht, B = wc1pk double-
//      buffered register bursts (L2-resident).
// Each h2 value computed exactly once across the grid (no redundant FLOPs);
// the V buffer and its 134MB round-trip are eliminated.
// Swizzle (both tiles, row stride multiple of 128B): phys16Bslot = s ^ (row&7).
__global__ __launch_bounds__(512) void fh2c1_k(
    const __hip_bfloat16* __restrict__ ybf,   // 65536 x 128
    const __hip_bfloat16* __restrict__ WTpk,  // packed (nkt=4)
    const float* __restrict__ bg,             // 512
    const __hip_bfloat16* __restrict__ wc1pk, // packed (nkt=64)
    const float* __restrict__ bc1,            // 512
    __hip_bfloat16* __restrict__ act1) {      // 16384 x 512
    __shared__ char yt[16384];   // [64][256B]
    __shared__ char ht[65536];   // [64][1024B]
    const int tid = threadIdx.x;
    const int lane = tid & 63, wid = tid >> 6;
    const int bx = blockIdx.x;
    const int l15 = lane & 15, lhi = lane >> 4;

    const __hip_bfloat16* Bp[4];
#pragma unroll
    for (int j = 0; j < 4; ++j)
        Bp[j] = wc1pk + ((size_t)(wid * 4 + j) * 64) * 512 + lane * 8;

    f32x4 acc[4][4] = {};

    for (int g = 0; g < 4; ++g) {
        __syncthreads();  // all waves done reading ht from previous segment
        // ---- 1. stage y-tile ----
#pragma unroll
        for (int q = 0; q < 2; ++q) {
            int a = wid * 8 + q * 4 + (lane >> 4);
            int node = bx * 256 + ((a >> 5) << 7) + g * 32 + (a & 31);
            int scol = ((lane & 15) ^ (a & 7)) << 4;  // pre-swizzled source col
            gll16((const char*)ybf + (size_t)node * 256 + scol,
                  yt + wid * 2048 + q * 1024 + lane * 16);
        }
        __syncthreads();  // vmcnt drained; y-tile ready

        // ---- 2. h2 sub-GEMM + tanh -> ht ----
        {
            f32x4 hacc[4][4] = {};
#pragma unroll
            for (int kt = 0; kt < 4; ++kt) {
                bf16x8 af[4], bfr[4];
#pragma unroll
                for (int i = 0; i < 4; ++i) {
                    int r = i * 16 + l15;
                    int s = (kt * 4 + lhi) ^ (r & 7);
                    af[i] = *(const bf16x8*)(yt + r * 256 + s * 16);
                }
#pragma unroll
                for (int j = 0; j < 4; ++j)
                    bfr[j] = *(const bf16x8*)(WTpk +
                        ((size_t)((wid * 4 + j) * 4 + kt) * 64 + lane) * 8);
#pragma unroll
                for (int i = 0; i < 4; ++i)
#pragma unroll
                    for (int j = 0; j < 4; ++j)
                        hacc[i][j] = __builtin_amdgcn_mfma_f32_16x16x32_bf16(
                            bfr[j], af[i], hacc[i][j], 0, 0, 0);
            }
#pragma unroll
            for (int j = 0; j < 4; ++j) {
                float4 bgv = *(const float4*)(bg + wid * 64 + j * 16 + lhi * 4);
                int bytecol = wid * 128 + j * 32 + lhi * 8;
                int s = bytecol >> 4;
                int off8 = bytecol & 15;  // 0 or 8
#pragma unroll
                for (int i = 0; i < 4; ++i) {
                    int row = i * 16 + l15;
                    alignas(8) unsigned short o[4];
#pragma unroll
                    for (int r = 0; r < 4; ++r) {
                        float v = hacc[i][j][r] + ((const float*)&bgv)[r];
                        v = 1.0f - 2.0f / (__expf(2.0f * v) + 1.0f);  // tanh
                        o[r] = f2bf(v);
                    }
                    *(uint2*)(ht + row * 1024 + ((s ^ (row & 7)) << 4) + off8) =
                        *(const uint2*)o;
                }
            }
        }
        __syncthreads();  // lgkm drained; ht ready

        // ---- 3. cnn1 inner: 16 barrier-free K-steps ----
        bf16x8 b0[4], b1[4];
#pragma unroll
        for (int j = 0; j < 4; ++j)
            b0[j] = *(const bf16x8*)(Bp[j] + (size_t)(g * 16) * 512);
#pragma unroll
        for (int kk = 0; kk < 16; kk += 2) {
#pragma unroll
            for (int j = 0; j < 4; ++j)
                b1[j] = *(const bf16x8*)(Bp[j] + (size_t)(g * 16 + kk + 1) * 512);
            {
                bf16x8 af[4];
#pragma unroll
                for (int i = 0; i < 4; ++i) {
                    int r = i * 16 + l15;
                    int s = (kk * 4 + lhi) ^ (r & 7);
                    af[i] = *(const bf16x8*)(ht + r * 1024 + s * 16);
                }
#pragma unroll
                for (int i = 0; i < 4; ++i)
#pragma unroll
                    for (int j = 0; j < 4; ++j)
                        acc[i][j] = __builtin_amdgcn_mfma_f32_16x16x32_bf16(
                            b0[j], af[i], acc[i][j], 0, 0, 0);
            }
            if (kk + 2 < 16) {
#pragma unroll
                for (int j = 0; j < 4; ++j)
                    b0[j] = *(const bf16x8*)(Bp[j] + (size_t)(g * 16 + kk + 2) * 512);
            }
            {
                bf16x8 af[4];
#pragma unroll
                for (int i = 0; i < 4; ++i) {
                    int r = i * 16 + l15;
                    int s = ((kk + 1) * 4 + lhi) ^ (r & 7);
                    af[i] = *(const bf16x8*)(ht + r * 1024 + s * 16);
                }
#pragma unroll
                for (int i = 0; i < 4; ++i)
#pragma unroll
                    for (int j = 0; j < 4; ++j)
                        acc[i][j] = __builtin_amdgcn_mfma_f32_16x16x32_bf16(
                            b1[j], af[i], acc[i][j], 0, 0, 0);
            }
        }
    }

    // ---- epilogue: relu + bias -> act1 (8B ushort4 stores) ----
#pragma unroll
    for (int i = 0; i < 4; ++i) {
        int m = bx * 64 + i * 16 + l15;
#pragma unroll
        for (int j = 0; j < 4; ++j) {
            int n = wid * 64 + j * 16 + lhi * 4;
            float4 bv = *(const float4*)(bc1 + n);
            ushort4 o;
#pragma unroll
            for (int r = 0; r < 4; ++r) {
                float v = fmaxf(acc[i][j][r] + ((const float*)&bv)[r], 0.f);
                ((unsigned short*)&o)[r] = f2bf(v);
            }
            *(ushort4*)((unsigned short*)act1 + (size_t)m * 512 + n) = o;
        }
    }
}

// ---------------- bf16 MFMA GEMM (128x128): cnn2 + final dot ------------------
// R15-verbatim (OUT_MODE 3 path), used only for cnn2+final.
template <int ACT, int OUT_MODE, int SWIZ_NTX>
__global__ __launch_bounds__(256) void gemm_mfma_k(
    const __hip_bfloat16* __restrict__ A, const __hip_bfloat16* __restrict__ B,
    const float* __restrict__ bias, void* __restrict__ Cout,
    const float* __restrict__ wlin, int M, int N, int K) {
    __shared__ char lds[65536];  // 4 bufs x (A 8KB | B 8KB)

    const int tid = threadIdx.x;
    const int lane = tid & 63, wid = tid >> 6;
    int bx, by;
    if (SWIZ_NTX > 0) {
        int orig = blockIdx.x;
        int per = gridDim.x / (8 * SWIZ_NTX);
        int xcd = orig & 7, k = orig >> 3;
        by = xcd * per + k / SWIZ_NTX;
        bx = k % SWIZ_NTX;
    } else {
        bx = blockIdx.x;
        by = blockIdx.y;
    }
    const int bm = by * 128, bn = bx * 128;
    const int wr = wid >> 1, wc = wid & 1;

    const int srow = wid * 16 + (lane >> 2);
    const int skcol = (((lane & 3) ^ ((lane >> 3) & 3))) * 8;
    const __hip_bfloat16* Abase = A + (size_t)(bm + srow) * K + skcol;
    const __hip_bfloat16* Bbase = B + (size_t)(bn + srow) * K + skcol;
    const int ldso = wid * 1024;

    f32x4 acc[4][4] = {};

    const int lrow = lane & 15;
    const int lkb = (((lane >> 4) ^ ((lane >> 1) & 3)) << 4);
    const int nk = K >> 5;

    auto stage = [&](int buf, int kt) {
        char* la = lds + buf * 16384;
        char* lb = la + 8192;
        gll16(Abase + kt * 32,                  la + ldso);
        gll16(Abase + kt * 32 + (size_t)64 * K, la + 4096 + ldso);
        gll16(Bbase + kt * 32,                  lb + ldso);
        gll16(Bbase + kt * 32 + (size_t)64 * K, lb + 4096 + ldso);
    };

    stage(0, 0);
    stage(1, 1);
    stage(2, 2);

    for (int kt = 0; kt < nk; ++kt) {
        int ahead = nk - 1 - kt;
        if (ahead >= 2)      asm volatile("s_waitcnt vmcnt(8)" ::: "memory");
        else if (ahead == 1) asm volatile("s_waitcnt vmcnt(4)" ::: "memory");
        else                 asm volatile("s_waitcnt vmcnt(0)" ::: "memory");
        __builtin_amdgcn_s_barrier();
        asm volatile("" ::: "memory");
        if (kt + 3 < nk) stage((kt + 3) & 3, kt + 3);

        const char* la = lds + (kt & 3) * 16384;
        const char* lb = la + 8192;
        bf16x8 af[4], bfr[4];
#pragma unroll
        for (int i = 0; i < 4; ++i)
            af[i] = *(const bf16x8*)(la + (wr * 64 + i * 16 + lrow) * 64 + lkb);
#pragma unroll
        for (int j = 0; j < 4; ++j)
            bfr[j] = *(const bf16x8*)(lb + (wc * 64 + j * 16 + lrow) * 64 + lkb);
        __builtin_amdgcn_s_setprio(1);
#pragma unroll
        for (int i = 0; i < 4; ++i)
#pragma unroll
            for (int j = 0; j < 4; ++j)
                acc[i][j] = __builtin_amdgcn_mfma_f32_16x16x32_bf16(
                    bfr[j], af[i], acc[i][j], 0, 0, 0);  // SWAPPED operands
        __builtin_amdgcn_s_setprio(0);
        asm volatile("" ::: "memory");
    }

    const int l15 = lane & 15, lhi = lane >> 4;

    if (OUT_MODE == 3) {
        float p0 = 0.f, p1 = 0.f;
#pragma unroll
        for (int i = 0; i < 4; ++i) {
            int e = (i & 1) * 16 + l15;  // m & 31
#pragma unroll
            for (int j = 0; j < 4; ++j) {
                int n = bn + wc * 64 + j * 16 + lhi * 4;
                float4 bv = *(const float4*)(bias + n);
#pragma unroll
                for (int r = 0; r < 4; ++r) {
                    float v = fmaxf(acc[i][j][r] + ((const float*)&bv)[r], 0.f);
                    float wl = wlin[(n + r) * 32 + e];
                    if (i < 2) p0 += v * wl; else p1 += v * wl;
                }
            }
        }
#pragma unroll
        for (int off = 32; off > 0; off >>= 1) {
            p0 += __shfl_down(p0, off, 64);
            p1 += __shfl_down(p1, off, 64);
        }
        if (lane == 0) {
            int g = (bm >> 5) + wr * 2;
            atomicAdd(&((float*)Cout)[g], p0);
            atomicAdd(&((float*)Cout)[g + 1], p1);
        }
        return;
    }

#pragma unroll
    for (int i = 0; i < 4; ++i) {
        int m = bm + wr * 64 + i * 16 + l15;
#pragma unroll
        for (int j = 0; j < 4; ++j) {
            int n = bn + wc * 64 + j * 16 + lhi * 4;
            float4 bv = *(const float4*)(bias + n);
            ushort4 o;
#pragma unroll
            for (int r = 0; r < 4; ++r) {
                float v = acc[i][j][r] + ((const float*)&bv)[r];
                if (ACT == 1) v = fmaxf(v, 0.f);
                ((unsigned short*)&o)[r] = f2bf(v);
            }
            *(ushort4*)((unsigned short*)Cout + (size_t)m * N + n) = o;
        }
    }
}

// ---------------- sigmoid over 512 graph logits --------------------------------
__global__ void sigmoid_k(const float* __restrict__ logits,
                          const float* __restrict__ blin, float* __restrict__ out) {
    int b = blockIdx.x * 256 + threadIdx.x;
    out[b] = 1.0f / (1.0f + expf(-(logits[b] + blin[0])));
}

extern "C" void kernel_launch(void* const* d_in, const int* in_sizes, int n_in,
                              void* d_out, int out_size, void* d_ws, size_t ws_size,
                              hipStream_t stream) {
    const float* x    = (const float*)d_in[0];
    const float* eattr= (const float*)d_in[1];
    const float* w1   = (const float*)d_in[2];
    const float* wg   = (const float*)d_in[3];
    const float* bg   = (const float*)d_in[4];
    const float* wc1  = (const float*)d_in[5];
    const float* bc1  = (const float*)d_in[6];
    const float* wc2  = (const float*)d_in[7];
    const float* bc2  = (const float*)d_in[8];
    const float* wlin = (const float*)d_in[9];
    const float* blin = (const float*)d_in[10];
    const int*   ei   = (const int*)d_in[11];
    const int* esrc = ei;
    const int* edst = ei + N_EDGES;
    float* out = (float*)d_out;

    // workspace layout (bytes, 16B aligned)
    char* ws = (char*)d_ws;
    float*          dinv   = (float*)(ws + 0);          // 262144
    int*            cnt    = (int*)(ws + 262144);       // 262144
    int*            rp     = (int*)(ws + 524288);       // 262160 (65537 ints)
    int*            cursor = (int*)(ws + 786688);       // 262144
    uint2*          ep     = (uint2*)(ws + 1048832);    // 4194304 (packed src,w)
    __hip_bfloat16* WTpk   = (__hip_bfloat16*)(ws + 5243136);   // 131072
    __hip_bfloat16* ybf    = (__hip_bfloat16*)(ws + 5374208);   // 16777216
    __hip_bfloat16* act1   = (__hip_bfloat16*)(ws + 89260288);  // 16777216
    __hip_bfloat16* wc1pk  = (__hip_bfloat16*)(ws + 106037504); // 2097152
    __hip_bfloat16* wc2bf  = (__hip_bfloat16*)(ws + 108134656); // 262144
    __hip_bfloat16* xbf    = (__hip_bfloat16*)(ws + 108396800); // 16777216
    float*          logits = (float*)(ws + 125174016);  // 2048
    int*            bsum   = (int*)(ws + 125176064);    // 1024
    if (ws_size < (size_t)125177088) return;

    // 1) init (cnt=0, logits=0)
    init_k<<<N_NODES / 256, 256, 0, stream>>>(cnt, logits);

    // 2) in-degree counts (int atomics only)
    cnt_k<<<N_EDGES / 256, 256, 0, stream>>>(edst, cnt);

    // 3) hierarchical scan -> rp, cursor
    scan1_k<<<256, 256, 0, stream>>>(cnt, rp, bsum);
    scan2_k<<<1, 256, 0, stream>>>(bsum, rp);
    scan3_k<<<256, 256, 0, stream>>>(rp, bsum, cursor);

    // 4) scatter edges into CSR, packed (src, w) 8B records
    scatter_k<<<N_EDGES / 256, 256, 0, stream>>>(esrc, edst, eattr, cursor, ep);

    // 5) degree via coalesced CSR row-sum -> dinv
    rowsum_k<<<N_NODES / 256, 256, 0, stream>>>(rp, ep, dinv);

    // 6) weight prep (wc1 packed, wc2 bf16, W_comb packed) + x' = bf16(dinv*x)
    wprep_k<<<896, 256, 0, stream>>>(wc1, wc1pk, wc2, wc2bf, w1, wg, WTpk);
    xscale_k<<<(N_NODES * 128 / 4) / 256, 256, 0, stream>>>(x, dinv, xbf);

    // 7) gather SpMM (8-deep ILP) -> ybf
    gather_k<<<N_NODES / 4, 256, 0, stream>>>(rp, ep,
                                              (const unsigned short*)xbf, dinv, ybf);

    // 8) FUSED h2 + cnn1 -> act1 (V buffer + dispatch eliminated)
    fh2c1_k<<<256, 512, 0, stream>>>(ybf, WTpk, bg, wc1pk, bc1, act1);

    // 9) cnn2 + final dot fused
    gemm_mfma_k<1, 3, 0><<<dim3(2, 128), 256, 0, stream>>>(
        act1, wc2bf, bc2, logits, wlin, 16384, 256, 512);

    // 10) sigmoid
    sigmoid_k<<<2, 256, 0, stream>>>(logits, blin, out);
}